// Round 2
// baseline (246.605 us; speedup 1.0000x reference)
//
#include <hip/hip_runtime.h>
#include <math.h>

#define N_AA    20
#define NATOM   15
#define D_FEAT  128
#define TM      32
#define FSTRIDE 88     // 48 coord (45 + 3 zero pad) + 40 dihedral (39 + 1 zero pad)
#define W1_N    256
#define ROW_COORD 128
#define ROW_DIH   1028
#define ROW_CHAIN 1067
#define BLK_TAB 1024

// ---------------- tables: aaT[g][j] = aa_emb[g] @ W1[0:128], chT[c][j] = chain_emb[c] @ W1[1067:1195]
__global__ __launch_bounds__(256) void tables_kernel(
    const float* __restrict__ aa_emb, const float* __restrict__ chain_emb,
    const float* __restrict__ W1, float* __restrict__ aaT, float* __restrict__ chT)
{
    const int t = threadIdx.x;
    const int b = blockIdx.x;
    if (b < N_AA) {
        const float* e = aa_emb + b * D_FEAT;
        float acc = 0.f;
        for (int k = 0; k < D_FEAT; ++k)
            acc += e[k] * W1[(size_t)k * W1_N + t];
        aaT[b * W1_N + t] = acc;
    } else {
        const int c = b - N_AA;
        const float* e = chain_emb + c * D_FEAT;
        float acc = 0.f;
        for (int k = 0; k < D_FEAT; ++k)
            acc += e[k] * W1[(size_t)(ROW_CHAIN + k) * W1_N + t];
        chT[c * W1_N + t] = acc;
    }
}

// ---------------- sort machinery: counting sort of rows by aa type ----------------
__global__ __launch_bounds__(256) void k1_hist(const int* __restrict__ seq, int* __restrict__ cnt)
{
    __shared__ int h[N_AA];
    const int t = threadIdx.x;
    if (t < N_AA) h[t] = 0;
    __syncthreads();
    atomicAdd(&h[seq[blockIdx.x * 256 + t]], 1);
    __syncthreads();
    if (t < N_AA) cnt[blockIdx.x * N_AA + t] = h[t];
}

__global__ __launch_bounds__(64) void k2_prefix(
    const int* __restrict__ cnt, int* __restrict__ off, int* __restrict__ bucket_start,
    int* __restrict__ blk_type, int* __restrict__ blk_chunk, int nchunks)
{
    __shared__ int tot[N_AA];
    __shared__ int bs[N_AA + 1];
    const int t = threadIdx.x;
    if (t < N_AA) {
        int s = 0;
        for (int c = 0; c < nchunks; ++c) s += cnt[c * N_AA + t];
        tot[t] = s;
    }
    for (int i = t; i < BLK_TAB; i += 64) blk_type[i] = -1;
    __syncthreads();
    if (t == 0) {
        int run = 0;
        for (int g = 0; g < N_AA; ++g) { bs[g] = run; run += tot[g]; }
        bs[N_AA] = run;
        for (int g = 0; g <= N_AA; ++g) bucket_start[g] = bs[g];
        int total = 0;
        for (int g = 0; g < N_AA; ++g) {
            const int nb = (tot[g] + TM - 1) / TM;
            for (int j = 0; j < nb; ++j) { blk_type[total] = g; blk_chunk[total] = j; ++total; }
        }
    }
    __syncthreads();
    if (t < N_AA) {
        int run = bs[t];
        for (int c = 0; c < nchunks; ++c) { off[c * N_AA + t] = run; run += cnt[c * N_AA + t]; }
    }
}

__global__ __launch_bounds__(256) void k3_scatter(
    const int* __restrict__ seq, const int* __restrict__ off, int* __restrict__ rowidx)
{
    __shared__ int cur[N_AA];
    const int t = threadIdx.x;
    if (t < N_AA) cur[t] = off[blockIdx.x * N_AA + t];
    __syncthreads();
    const int i = blockIdx.x * 256 + t;
    const int pos = atomicAdd(&cur[seq[i]], 1);
    rowidx[pos] = i;
}

__device__ __forceinline__ float4 relu4(float4 v) {
    float4 o;
    o.x = fmaxf(v.x, 0.f); o.y = fmaxf(v.y, 0.f);
    o.z = fmaxf(v.z, 0.f); o.w = fmaxf(v.w, 0.f);
    return o;
}

// ---------------- fused: features + 4-layer MLP, 32 same-type rows per block
__global__ __launch_bounds__(256, 3) void fused_kernel(
    const int* __restrict__ chain_idx, const float* __restrict__ xyz,
    const float* __restrict__ dihedrals, const float* __restrict__ orientation,
    const float* __restrict__ W1, const float* __restrict__ b1,
    const float* __restrict__ W2, const float* __restrict__ b2,
    const float* __restrict__ W3, const float* __restrict__ b3,
    const float* __restrict__ W4, const float* __restrict__ b4,
    const float* __restrict__ aaT, const float* __restrict__ chT,
    const int* __restrict__ bucket_start, const int* __restrict__ blk_type,
    const int* __restrict__ blk_chunk, const int* __restrict__ rowidx,
    float* __restrict__ out)
{
    __shared__ __align__(16) float bufA[TM][128];   // feat (uses [0..87]) then h2
    __shared__ __align__(16) float bufB[TM][256];   // h1 then h3
    __shared__ int s_row[TM];      // original row id, or -1 for pad
    __shared__ int s_rowld[TM];    // clamped row id for loads
    __shared__ int s_chain[TM];

    float (*feat)[128] = bufA;
    float (*h1)[256]   = bufB;
    float (*h2)[128]   = bufA;
    float (*h3)[128]   = (float(*)[128])bufB;

    const int t = threadIdx.x;
    const int g = blk_type[blockIdx.x];
    if (g < 0) return;
    const int chunk  = blk_chunk[blockIdx.x];
    const int bstart = bucket_start[g] + chunk * TM;
    const int nrows  = min(TM, bucket_start[g + 1] - bstart);

    if (t < TM) {
        const bool valid = (t < nrows);
        const int rl = rowidx[valid ? (bstart + t) : bstart];
        s_row[t]   = valid ? rl : -1;
        s_rowld[t] = rl;
        s_chain[t] = chain_idx[rl];
        feat[t][45] = 0.f; feat[t][46] = 0.f; feat[t][47] = 0.f;  // coord pad
        feat[t][87] = 0.f;                                        // dihedral pad
    }
    __syncthreads();

    // ---- coord features: xyz_local = O^T (xyz - CA) ----
    for (int p = t; p < TM * NATOM; p += 256) {
        const int r = p / NATOM, a = p % NATOM;
        const int rl = s_rowld[r];
        const float* xr = xyz + (size_t)rl * (NATOM * 3);
        const float cax = xr[3], cay = xr[4], caz = xr[5];   // CA_IDX = 1
        const float rx = xr[a*3+0] - cax;
        const float ry = xr[a*3+1] - cay;
        const float rz = xr[a*3+2] - caz;
        const float* O = orientation + (size_t)rl * 9;
        feat[r][a*3+0] = O[0]*rx + O[3]*ry + O[6]*rz;
        feat[r][a*3+1] = O[1]*rx + O[4]*ry + O[7]*rz;
        feat[r][a*3+2] = O[2]*rx + O[5]*ry + O[8]*rz;
    }

    // ---- dihedral angular encoding ----
    if (t < TM * 3) {
        const int r = t / 3, d = t % 3;
        const float x = dihedrals[(size_t)s_rowld[r] * 3 + d];
        float* f = &feat[r][48 + d * 13];
        const float F3 = (float)(1.0 / 3.0);
        f[0]  = x;
        f[1]  = sinf(1.0f * x); f[2]  = sinf(2.0f * x); f[3]  = sinf(3.0f * x);
        f[4]  = sinf(1.0f * x); f[5]  = sinf(0.5f * x); f[6]  = sinf(F3 * x);
        f[7]  = cosf(1.0f * x); f[8]  = cosf(2.0f * x); f[9]  = cosf(3.0f * x);
        f[10] = cosf(1.0f * x); f[11] = cosf(0.5f * x); f[12] = cosf(F3 * x);
    }
    __syncthreads();

    // ---- layer 1: weights are block-uniform (all rows same aa type) -> registers ----
    {
        float wc[48];   // coord weights (3 pads multiply zero feat slots; rows exist in W1)
        #pragma unroll
        for (int k = 0; k < 48; ++k)
            wc[k] = W1[(size_t)(ROW_COORD + g * 45 + k) * W1_N + t];
        float wd[40];   // dihedral weights (1 pad)
        #pragma unroll
        for (int k = 0; k < 40; ++k)
            wd[k] = W1[(size_t)(ROW_DIH + k) * W1_N + t];
        const float base = b1[t] + aaT[g * W1_N + t];

        for (int r = 0; r < TM; ++r) {
            float acc = base + chT[s_chain[r] * W1_N + t];
            const float4* f4 = (const float4*)&feat[r][0];
            #pragma unroll
            for (int k4 = 0; k4 < 12; ++k4) {
                const float4 f = f4[k4];
                acc += f.x * wc[k4*4+0];
                acc += f.y * wc[k4*4+1];
                acc += f.z * wc[k4*4+2];
                acc += f.w * wc[k4*4+3];
            }
            const float4* fd4 = (const float4*)&feat[r][48];
            #pragma unroll
            for (int k4 = 0; k4 < 10; ++k4) {
                const float4 f = fd4[k4];
                acc += f.x * wd[k4*4+0];
                acc += f.y * wd[k4*4+1];
                acc += f.z * wd[k4*4+2];
                acc += f.w * wd[k4*4+3];
            }
            h1[r][t] = fmaxf(acc, 0.f);
        }
    }
    __syncthreads();   // feat dead after this; h2 may overwrite bufA

    const int rg = t >> 5;
    const int cg = t & 31;
    const int r0 = rg * 4, j0 = cg * 4;

    // ---- layer 2: h2 = relu(h1 @ W2 + b2), K=256 ----
    {
        const float4 bv = *(const float4*)&b2[j0];
        float4 c0 = bv, c1 = bv, c2 = bv, c3 = bv;
        for (int k = 0; k < 256; k += 4) {
            float a0v[4], a1v[4], a2v[4], a3v[4];
            *(float4*)a0v = *(const float4*)&h1[r0+0][k];
            *(float4*)a1v = *(const float4*)&h1[r0+1][k];
            *(float4*)a2v = *(const float4*)&h1[r0+2][k];
            *(float4*)a3v = *(const float4*)&h1[r0+3][k];
            #pragma unroll
            for (int kk = 0; kk < 4; ++kk) {
                const float4 w = *(const float4*)&W2[(size_t)(k+kk)*128 + j0];
                c0.x += a0v[kk]*w.x; c0.y += a0v[kk]*w.y; c0.z += a0v[kk]*w.z; c0.w += a0v[kk]*w.w;
                c1.x += a1v[kk]*w.x; c1.y += a1v[kk]*w.y; c1.z += a1v[kk]*w.z; c1.w += a1v[kk]*w.w;
                c2.x += a2v[kk]*w.x; c2.y += a2v[kk]*w.y; c2.z += a2v[kk]*w.z; c2.w += a2v[kk]*w.w;
                c3.x += a3v[kk]*w.x; c3.y += a3v[kk]*w.y; c3.z += a3v[kk]*w.z; c3.w += a3v[kk]*w.w;
            }
        }
        *(float4*)&h2[r0+0][j0] = relu4(c0);
        *(float4*)&h2[r0+1][j0] = relu4(c1);
        *(float4*)&h2[r0+2][j0] = relu4(c2);
        *(float4*)&h2[r0+3][j0] = relu4(c3);
    }
    __syncthreads();   // h1 dead after this; h3 may overwrite bufB

    // ---- layer 3: h3 = relu(h2 @ W3 + b3), K=128 ----
    {
        const float4 bv = *(const float4*)&b3[j0];
        float4 c0 = bv, c1 = bv, c2 = bv, c3 = bv;
        for (int k = 0; k < 128; k += 4) {
            float a0v[4], a1v[4], a2v[4], a3v[4];
            *(float4*)a0v = *(const float4*)&h2[r0+0][k];
            *(float4*)a1v = *(const float4*)&h2[r0+1][k];
            *(float4*)a2v = *(const float4*)&h2[r0+2][k];
            *(float4*)a3v = *(const float4*)&h2[r0+3][k];
            #pragma unroll
            for (int kk = 0; kk < 4; ++kk) {
                const float4 w = *(const float4*)&W3[(size_t)(k+kk)*128 + j0];
                c0.x += a0v[kk]*w.x; c0.y += a0v[kk]*w.y; c0.z += a0v[kk]*w.z; c0.w += a0v[kk]*w.w;
                c1.x += a1v[kk]*w.x; c1.y += a1v[kk]*w.y; c1.z += a1v[kk]*w.z; c1.w += a1v[kk]*w.w;
                c2.x += a2v[kk]*w.x; c2.y += a2v[kk]*w.y; c2.z += a2v[kk]*w.z; c2.w += a2v[kk]*w.w;
                c3.x += a3v[kk]*w.x; c3.y += a3v[kk]*w.y; c3.z += a3v[kk]*w.z; c3.w += a3v[kk]*w.w;
            }
        }
        __syncthreads();   // all h1 reads done before overwriting bufB
        *(float4*)&h3[r0+0][j0] = relu4(c0);
        *(float4*)&h3[r0+1][j0] = relu4(c1);
        *(float4*)&h3[r0+2][j0] = relu4(c2);
        *(float4*)&h3[r0+3][j0] = relu4(c3);
    }
    __syncthreads();

    // ---- layer 4: out = h3 @ W4 + b4, scatter to original rows ----
    {
        const float4 bv = *(const float4*)&b4[j0];
        float4 c0 = bv, c1 = bv, c2 = bv, c3 = bv;
        for (int k = 0; k < 128; k += 4) {
            float a0v[4], a1v[4], a2v[4], a3v[4];
            *(float4*)a0v = *(const float4*)&h3[r0+0][k];
            *(float4*)a1v = *(const float4*)&h3[r0+1][k];
            *(float4*)a2v = *(const float4*)&h3[r0+2][k];
            *(float4*)a3v = *(const float4*)&h3[r0+3][k];
            #pragma unroll
            for (int kk = 0; kk < 4; ++kk) {
                const float4 w = *(const float4*)&W4[(size_t)(k+kk)*128 + j0];
                c0.x += a0v[kk]*w.x; c0.y += a0v[kk]*w.y; c0.z += a0v[kk]*w.z; c0.w += a0v[kk]*w.w;
                c1.x += a1v[kk]*w.x; c1.y += a1v[kk]*w.y; c1.z += a1v[kk]*w.z; c1.w += a1v[kk]*w.w;
                c2.x += a2v[kk]*w.x; c2.y += a2v[kk]*w.y; c2.z += a2v[kk]*w.z; c2.w += a2v[kk]*w.w;
                c3.x += a3v[kk]*w.x; c3.y += a3v[kk]*w.y; c3.z += a3v[kk]*w.z; c3.w += a3v[kk]*w.w;
            }
        }
        float4 cs[4] = {c0, c1, c2, c3};
        #pragma unroll
        for (int i = 0; i < 4; ++i) {
            const int orow = s_row[r0 + i];
            if (orow >= 0)
                *(float4*)&out[(size_t)orow * 128 + j0] = cs[i];
        }
    }
}

extern "C" void kernel_launch(void* const* d_in, const int* in_sizes, int n_in,
                              void* d_out, int out_size, void* d_ws, size_t ws_size,
                              hipStream_t stream) {
    const int*   seq    = (const int*)d_in[0];
    const float* xyz    = (const float*)d_in[1];
    const float* dihed  = (const float*)d_in[2];
    const int*   chain  = (const int*)d_in[3];
    const float* orient = (const float*)d_in[4];
    // d_in[5] = atom_mask: unused by the reference
    const float* aa_emb = (const float*)d_in[6];
    const float* ch_emb = (const float*)d_in[7];
    const float* W1 = (const float*)d_in[8];
    const float* b1 = (const float*)d_in[9];
    const float* W2 = (const float*)d_in[10];
    const float* b2 = (const float*)d_in[11];
    const float* W3 = (const float*)d_in[12];
    const float* b3 = (const float*)d_in[13];
    const float* W4 = (const float*)d_in[14];
    const float* b4 = (const float*)d_in[15];
    float* out = (float*)d_out;

    const int BL = in_sizes[0];           // 16384 rows
    const int nchunks = BL / 256;         // 64

    // workspace layout
    float* aaT = (float*)d_ws;                       // 20*256
    float* chT = aaT + N_AA * W1_N;                  // 10*256
    int* cnt          = (int*)(chT + 10 * W1_N);     // nchunks*20
    int* off          = cnt + nchunks * N_AA;        // nchunks*20
    int* bucket_start = off + nchunks * N_AA;        // 21
    int* blk_type     = bucket_start + 32;           // BLK_TAB
    int* blk_chunk    = blk_type + BLK_TAB;          // BLK_TAB
    int* rowidx       = blk_chunk + BLK_TAB;         // BL

    const int nfused = BL / TM + N_AA;    // upper bound on type-pure blocks

    tables_kernel<<<N_AA + 10, 256, 0, stream>>>(aa_emb, ch_emb, W1, aaT, chT);
    k1_hist<<<nchunks, 256, 0, stream>>>(seq, cnt);
    k2_prefix<<<1, 64, 0, stream>>>(cnt, off, bucket_start, blk_type, blk_chunk, nchunks);
    k3_scatter<<<nchunks, 256, 0, stream>>>(seq, off, rowidx);
    fused_kernel<<<nfused, 256, 0, stream>>>(chain, xyz, dihed, orient,
                                             W1, b1, W2, b2, W3, b3, W4, b4,
                                             aaT, chT, bucket_start, blk_type, blk_chunk, rowidx,
                                             out);
}

// Round 4
// 219.330 us; speedup vs baseline: 1.1244x; 1.1244x over previous
//
#include <hip/hip_runtime.h>
#include <math.h>

#define N_AA    20
#define NATOM   15
#define D_FEAT  128
#define TM      16
#define W1_N    256
#define ROW_COORD 128
#define ROW_DIH   1028
#define ROW_CHAIN 1067
#define MAXBL   16384
#define MAXBLK  (MAXBL / TM + N_AA)   // 1044

// ---------------- prep: blocks 0..29 = tables, block 30 = counting sort ----------------
__global__ __launch_bounds__(1024) void prep_kernel(
    const int* __restrict__ seq, const float* __restrict__ aa_emb,
    const float* __restrict__ chain_emb, const float* __restrict__ W1,
    int BL,
    float* __restrict__ aaT, float* __restrict__ chT,
    int* __restrict__ bucket_start, int* __restrict__ blk_type,
    int* __restrict__ blk_chunk, int* __restrict__ rowidx)
{
    const int t = threadIdx.x;
    const int b = blockIdx.x;

    if (b < 30) {
        if (t < W1_N) {
            if (b < N_AA) {
                const float* e = aa_emb + b * D_FEAT;
                float acc = 0.f;
                #pragma unroll 8
                for (int k = 0; k < D_FEAT; ++k)
                    acc += e[k] * W1[(size_t)k * W1_N + t];
                aaT[b * W1_N + t] = acc;
            } else {
                const int c = b - N_AA;
                const float* e = chain_emb + c * D_FEAT;
                float acc = 0.f;
                #pragma unroll 8
                for (int k = 0; k < D_FEAT; ++k)
                    acc += e[k] * W1[(size_t)(ROW_CHAIN + k) * W1_N + t];
                chT[c * W1_N + t] = acc;
            }
        }
        return;
    }

    // ---- block 30: counting sort of rows by aa type ----
    __shared__ int sseq[MAXBL];
    __shared__ int hist[16][N_AA];
    __shared__ int bs[N_AA + 1];
    __shared__ int cur[N_AA];

    const int w = t >> 6;
    for (int i = t; i < BL; i += 1024) sseq[i] = seq[i];
    if (t < 16 * N_AA) hist[t / N_AA][t % N_AA] = 0;
    for (int i = t; i < MAXBLK; i += 1024) blk_type[i] = -1;
    __syncthreads();

    for (int i = t; i < BL; i += 1024) atomicAdd(&hist[w][sseq[i]], 1);
    __syncthreads();

    if (t == 0) {
        int run = 0;
        for (int g = 0; g < N_AA; ++g) {
            int s = 0;
            for (int ww = 0; ww < 16; ++ww) s += hist[ww][g];
            bs[g] = run; cur[g] = run; run += s;
        }
        bs[N_AA] = run;
        for (int g = 0; g <= N_AA; ++g) bucket_start[g] = bs[g];
        int total = 0;
        for (int g = 0; g < N_AA; ++g) {
            const int cntg = bs[g + 1] - bs[g];
            const int nb = (cntg + TM - 1) / TM;
            for (int j = 0; j < nb; ++j) { blk_type[total] = g; blk_chunk[total] = j; ++total; }
        }
    }
    __syncthreads();

    for (int i = t; i < BL; i += 1024) {
        const int pos = atomicAdd(&cur[sseq[i]], 1);
        rowidx[pos] = i;
    }
}

__device__ __forceinline__ float4 relu4(float4 v) {
    float4 o;
    o.x = fmaxf(v.x, 0.f); o.y = fmaxf(v.y, 0.f);
    o.z = fmaxf(v.z, 0.f); o.w = fmaxf(v.w, 0.f);
    return o;
}

// ---------------- fused: features + 4-layer MLP, 16 same-type rows per block ----------------
__global__ __launch_bounds__(256, 4) void fused_kernel(
    const int* __restrict__ chain_idx, const float* __restrict__ xyz,
    const float* __restrict__ dihedrals, const float* __restrict__ orientation,
    const float* __restrict__ W1, const float* __restrict__ b1,
    const float* __restrict__ W2, const float* __restrict__ b2,
    const float* __restrict__ W3, const float* __restrict__ b3,
    const float* __restrict__ W4, const float* __restrict__ b4,
    const float* __restrict__ aaT, const float* __restrict__ chT,
    const int* __restrict__ bucket_start, const int* __restrict__ blk_type,
    const int* __restrict__ blk_chunk, const int* __restrict__ rowidx,
    float* __restrict__ out)
{
    __shared__ __align__(16) float bufA[TM][128];   // feat (uses [0..87]) then h2
    __shared__ __align__(16) float bufB[TM][256];   // h1 then h3
    __shared__ int s_row[TM];
    __shared__ int s_rowld[TM];
    __shared__ int s_chain[TM];

    float (*feat)[128] = bufA;
    float (*h1)[256]   = bufB;
    float (*h2)[128]   = bufA;
    float (*h3)[128]   = (float(*)[128])bufB;

    const int t = threadIdx.x;
    const int g = blk_type[blockIdx.x];
    if (g < 0) return;
    const int chunk  = blk_chunk[blockIdx.x];
    const int bstart = bucket_start[g] + chunk * TM;
    const int nrows  = min(TM, bucket_start[g + 1] - bstart);

    if (t < TM) {
        const bool valid = (t < nrows);
        const int rl = rowidx[valid ? (bstart + t) : bstart];
        s_row[t]   = valid ? rl : -1;
        s_rowld[t] = rl;
        s_chain[t] = chain_idx[rl];
        feat[t][45] = 0.f; feat[t][46] = 0.f; feat[t][47] = 0.f;  // coord pad
        feat[t][87] = 0.f;                                        // dihedral pad
    }
    __syncthreads();

    // ---- coord features: xyz_local = O^T (xyz - CA) ----
    if (t < TM * NATOM) {
        const int r = t / NATOM, a = t % NATOM;
        const int rl = s_rowld[r];
        const float* xr = xyz + (size_t)rl * (NATOM * 3);
        const float cax = xr[3], cay = xr[4], caz = xr[5];   // CA_IDX = 1
        const float rx = xr[a*3+0] - cax;
        const float ry = xr[a*3+1] - cay;
        const float rz = xr[a*3+2] - caz;
        const float* O = orientation + (size_t)rl * 9;
        feat[r][a*3+0] = O[0]*rx + O[3]*ry + O[6]*rz;
        feat[r][a*3+1] = O[1]*rx + O[4]*ry + O[7]*rz;
        feat[r][a*3+2] = O[2]*rx + O[5]*ry + O[8]*rz;
    }

    // ---- dihedral angular encoding ----
    if (t < TM * 3) {
        const int r = t / 3, d = t % 3;
        const float x = dihedrals[(size_t)s_rowld[r] * 3 + d];
        float* f = &feat[r][48 + d * 13];
        const float F3 = (float)(1.0 / 3.0);
        f[0]  = x;
        f[1]  = sinf(1.0f * x); f[2]  = sinf(2.0f * x); f[3]  = sinf(3.0f * x);
        f[4]  = sinf(1.0f * x); f[5]  = sinf(0.5f * x); f[6]  = sinf(F3 * x);
        f[7]  = cosf(1.0f * x); f[8]  = cosf(2.0f * x); f[9]  = cosf(3.0f * x);
        f[10] = cosf(1.0f * x); f[11] = cosf(0.5f * x); f[12] = cosf(F3 * x);
    }
    __syncthreads();

    // ---- layer 1, phase A: coord part (48 weight regs live) ----
    {
        float wc[48];
        #pragma unroll
        for (int k = 0; k < 48; ++k)
            wc[k] = W1[(size_t)(ROW_COORD + g * 45 + k) * W1_N + t];
        for (int r = 0; r < TM; ++r) {
            const float4* f4 = (const float4*)&feat[r][0];
            float acc0 = 0.f, acc1 = 0.f;
            #pragma unroll
            for (int k4 = 0; k4 < 12; k4 += 2) {
                const float4 fa = f4[k4], fb = f4[k4+1];
                acc0 += fa.x * wc[k4*4+0]; acc0 += fa.y * wc[k4*4+1];
                acc0 += fa.z * wc[k4*4+2]; acc0 += fa.w * wc[k4*4+3];
                acc1 += fb.x * wc[k4*4+4]; acc1 += fb.y * wc[k4*4+5];
                acc1 += fb.z * wc[k4*4+6]; acc1 += fb.w * wc[k4*4+7];
            }
            h1[r][t] = acc0 + acc1;   // partial (no relu yet)
        }
    }
    // ---- layer 1, phase B: dihedral + base + relu (40 weight regs live) ----
    {
        float wd[40];
        #pragma unroll
        for (int k = 0; k < 40; ++k)
            wd[k] = W1[(size_t)(ROW_DIH + k) * W1_N + t];
        const float base = b1[t] + aaT[g * W1_N + t];
        for (int r = 0; r < TM; ++r) {
            const float4* fd4 = (const float4*)&feat[r][48];
            float acc0 = base + chT[s_chain[r] * W1_N + t] + h1[r][t];
            float acc1 = 0.f;
            #pragma unroll
            for (int k4 = 0; k4 < 10; k4 += 2) {
                const float4 fa = fd4[k4], fb = fd4[k4+1];
                acc0 += fa.x * wd[k4*4+0]; acc0 += fa.y * wd[k4*4+1];
                acc0 += fa.z * wd[k4*4+2]; acc0 += fa.w * wd[k4*4+3];
                acc1 += fb.x * wd[k4*4+4]; acc1 += fb.y * wd[k4*4+5];
                acc1 += fb.z * wd[k4*4+6]; acc1 += fb.w * wd[k4*4+7];
            }
            h1[r][t] = fmaxf(acc0 + acc1, 0.f);
        }
    }
    __syncthreads();   // h1 complete; feat dead -> h2 may overwrite bufA

    const int rg = t >> 5;          // 0..7
    const int cg = t & 31;          // 0..31
    const int r0 = rg * 2, j0 = cg * 4;

    // ---- layer 2: h2 = relu(h1 @ W2 + b2), K=256 ----
    {
        const float4 bv = *(const float4*)&b2[j0];
        float4 c0 = bv, c1 = bv;
        for (int k = 0; k < 256; k += 4) {
            float a0v[4], a1v[4];
            *(float4*)a0v = *(const float4*)&h1[r0+0][k];
            *(float4*)a1v = *(const float4*)&h1[r0+1][k];
            #pragma unroll
            for (int kk = 0; kk < 4; ++kk) {
                const float4 wv = *(const float4*)&W2[(size_t)(k+kk)*128 + j0];
                c0.x += a0v[kk]*wv.x; c0.y += a0v[kk]*wv.y; c0.z += a0v[kk]*wv.z; c0.w += a0v[kk]*wv.w;
                c1.x += a1v[kk]*wv.x; c1.y += a1v[kk]*wv.y; c1.z += a1v[kk]*wv.z; c1.w += a1v[kk]*wv.w;
            }
        }
        __syncthreads();   // all reads of bufA (feat) and h1 for this layer done before h2 overwrites bufA
        *(float4*)&h2[r0+0][j0] = relu4(c0);
        *(float4*)&h2[r0+1][j0] = relu4(c1);
    }
    __syncthreads();   // h2 complete; h1 dead -> h3 may overwrite bufB

    // ---- layer 3: h3 = relu(h2 @ W3 + b3), K=128 ----
    {
        const float4 bv = *(const float4*)&b3[j0];
        float4 c0 = bv, c1 = bv;
        for (int k = 0; k < 128; k += 4) {
            float a0v[4], a1v[4];
            *(float4*)a0v = *(const float4*)&h2[r0+0][k];
            *(float4*)a1v = *(const float4*)&h2[r0+1][k];
            #pragma unroll
            for (int kk = 0; kk < 4; ++kk) {
                const float4 wv = *(const float4*)&W3[(size_t)(k+kk)*128 + j0];
                c0.x += a0v[kk]*wv.x; c0.y += a0v[kk]*wv.y; c0.z += a0v[kk]*wv.z; c0.w += a0v[kk]*wv.w;
                c1.x += a1v[kk]*wv.x; c1.y += a1v[kk]*wv.y; c1.z += a1v[kk]*wv.z; c1.w += a1v[kk]*wv.w;
            }
        }
        *(float4*)&h3[r0+0][j0] = relu4(c0);
        *(float4*)&h3[r0+1][j0] = relu4(c1);
    }
    __syncthreads();   // h3 complete

    // ---- layer 4: out = h3 @ W4 + b4, scatter to original rows ----
    {
        const float4 bv = *(const float4*)&b4[j0];
        float4 c0 = bv, c1 = bv;
        for (int k = 0; k < 128; k += 4) {
            float a0v[4], a1v[4];
            *(float4*)a0v = *(const float4*)&h3[r0+0][k];
            *(float4*)a1v = *(const float4*)&h3[r0+1][k];
            #pragma unroll
            for (int kk = 0; kk < 4; ++kk) {
                const float4 wv = *(const float4*)&W4[(size_t)(k+kk)*128 + j0];
                c0.x += a0v[kk]*wv.x; c0.y += a0v[kk]*wv.y; c0.z += a0v[kk]*wv.z; c0.w += a0v[kk]*wv.w;
                c1.x += a1v[kk]*wv.x; c1.y += a1v[kk]*wv.y; c1.z += a1v[kk]*wv.z; c1.w += a1v[kk]*wv.w;
            }
        }
        const int o0 = s_row[r0 + 0];
        const int o1 = s_row[r0 + 1];
        if (o0 >= 0) *(float4*)&out[(size_t)o0 * 128 + j0] = c0;
        if (o1 >= 0) *(float4*)&out[(size_t)o1 * 128 + j0] = c1;
    }
}

extern "C" void kernel_launch(void* const* d_in, const int* in_sizes, int n_in,
                              void* d_out, int out_size, void* d_ws, size_t ws_size,
                              hipStream_t stream) {
    const int*   seq    = (const int*)d_in[0];
    const float* xyz    = (const float*)d_in[1];
    const float* dihed  = (const float*)d_in[2];
    const int*   chain  = (const int*)d_in[3];
    const float* orient = (const float*)d_in[4];
    // d_in[5] = atom_mask: unused by the reference
    const float* aa_emb = (const float*)d_in[6];
    const float* ch_emb = (const float*)d_in[7];
    const float* W1 = (const float*)d_in[8];
    const float* b1 = (const float*)d_in[9];
    const float* W2 = (const float*)d_in[10];
    const float* b2 = (const float*)d_in[11];
    const float* W3 = (const float*)d_in[12];
    const float* b3 = (const float*)d_in[13];
    const float* W4 = (const float*)d_in[14];
    const float* b4 = (const float*)d_in[15];
    float* out = (float*)d_out;

    const int BL = in_sizes[0];           // 16384 rows

    // workspace layout
    float* aaT = (float*)d_ws;                       // 20*256
    float* chT = aaT + N_AA * W1_N;                  // 10*256
    int* bucket_start = (int*)(chT + 10 * W1_N);     // 32
    int* blk_type     = bucket_start + 32;           // MAXBLK
    int* blk_chunk    = blk_type + MAXBLK;           // MAXBLK
    int* rowidx       = blk_chunk + MAXBLK;          // BL

    const int nfused = BL / TM + N_AA;

    prep_kernel<<<31, 1024, 0, stream>>>(seq, aa_emb, ch_emb, W1, BL,
                                         aaT, chT, bucket_start, blk_type, blk_chunk, rowidx);
    fused_kernel<<<nfused, 256, 0, stream>>>(chain, xyz, dihed, orient,
                                             W1, b1, W2, b2, W3, b3, W4, b4,
                                             aaT, chT, bucket_start, blk_type, blk_chunk, rowidx,
                                             out);
}

// Round 5
// 199.044 us; speedup vs baseline: 1.2389x; 1.1019x over previous
//
#include <hip/hip_runtime.h>
#include <math.h>

#define N_AA    20
#define NATOM   15
#define D_FEAT  128
#define TM      16
#define W1_N    256
#define ROW_COORD 128
#define ROW_DIH   1028
#define ROW_CHAIN 1067
#define MAXBL   16384
#define MAXBLK  (MAXBL / TM + N_AA)   // 1044
#define NWAVE   16

// ---------------- prep: blocks 0..29 = tables, block 30 = counting sort ----------------
__global__ __launch_bounds__(1024) void prep_kernel(
    const int* __restrict__ seq, const float* __restrict__ aa_emb,
    const float* __restrict__ chain_emb, const float* __restrict__ W1,
    int BL,
    float* __restrict__ aaT, float* __restrict__ chT,
    int* __restrict__ bucket_start, int* __restrict__ blk_type,
    int* __restrict__ blk_chunk, int* __restrict__ rowidx)
{
    const int t = threadIdx.x;
    const int b = blockIdx.x;

    if (b < 30) {
        if (t < W1_N) {
            if (b < N_AA) {
                const float* e = aa_emb + b * D_FEAT;
                float acc = 0.f;
                #pragma unroll 8
                for (int k = 0; k < D_FEAT; ++k)
                    acc += e[k] * W1[(size_t)k * W1_N + t];
                aaT[b * W1_N + t] = acc;
            } else {
                const int c = b - N_AA;
                const float* e = chain_emb + c * D_FEAT;
                float acc = 0.f;
                #pragma unroll 8
                for (int k = 0; k < D_FEAT; ++k)
                    acc += e[k] * W1[(size_t)(ROW_CHAIN + k) * W1_N + t];
                chT[c * W1_N + t] = acc;
            }
        }
        return;
    }

    // ---- block 30: counting sort of rows by aa type (parallelized) ----
    __shared__ int sseq[MAXBL];
    __shared__ int hist[NWAVE][N_AA];    // per-wave histograms
    __shared__ int wcur[NWAVE][N_AA];    // per-wave scatter cursors
    __shared__ int bs[N_AA + 1];         // bucket starts (rows)
    __shared__ int blkoff[N_AA + 1];     // block-table offsets per type

    const int w = t >> 6;

    for (int i = t; i < BL; i += 1024) sseq[i] = seq[i];
    if (t < NWAVE * N_AA) hist[t / N_AA][t % N_AA] = 0;
    __syncthreads();

    // per-wave histogram (contention only within a wave)
    for (int i = t; i < BL; i += 1024) atomicAdd(&hist[w][sseq[i]], 1);
    __syncthreads();

    // prefix sums over 20 buckets (trivial serial work on t==0)
    if (t == 0) {
        int runr = 0, runb = 0;
        for (int g = 0; g < N_AA; ++g) {
            int s = 0;
            #pragma unroll
            for (int ww = 0; ww < NWAVE; ++ww) s += hist[ww][g];
            bs[g] = runr; runr += s;
            blkoff[g] = runb; runb += (s + TM - 1) / TM;
        }
        bs[N_AA] = runr;
        blkoff[N_AA] = runb;
    }
    __syncthreads();

    if (t <= N_AA) bucket_start[t] = bs[t];

    // per-wave exclusive scatter offsets
    if (t < NWAVE * N_AA) {
        const int w2 = t / N_AA, g2 = t % N_AA;
        int o = bs[g2];
        for (int ww = 0; ww < w2; ++ww) o += hist[ww][g2];
        wcur[w2][g2] = o;
    }

    // parallel block-table build
    const int nblk = blkoff[N_AA];
    for (int i = t; i < MAXBLK; i += 1024) {
        if (i < nblk) {
            int g = 0;
            while (blkoff[g + 1] <= i) ++g;    // <=20 steps
            blk_type[i]  = g;
            blk_chunk[i] = i - blkoff[g];
        } else {
            blk_type[i] = -1;
        }
    }
    __syncthreads();

    // scatter: each wave uses its private cursors (within-wave contention only)
    for (int i = t; i < BL; i += 1024) {
        const int pos = atomicAdd(&wcur[w][sseq[i]], 1);
        rowidx[pos] = i;
    }
}

__device__ __forceinline__ float4 relu4(float4 v) {
    float4 o;
    o.x = fmaxf(v.x, 0.f); o.y = fmaxf(v.y, 0.f);
    o.z = fmaxf(v.z, 0.f); o.w = fmaxf(v.w, 0.f);
    return o;
}

// ---------------- fused: features + 4-layer MLP, 16 same-type rows per block ----------------
__global__ __launch_bounds__(256, 4) void fused_kernel(
    const int* __restrict__ chain_idx, const float* __restrict__ xyz,
    const float* __restrict__ dihedrals, const float* __restrict__ orientation,
    const float* __restrict__ W1, const float* __restrict__ b1,
    const float* __restrict__ W2, const float* __restrict__ b2,
    const float* __restrict__ W3, const float* __restrict__ b3,
    const float* __restrict__ W4, const float* __restrict__ b4,
    const float* __restrict__ aaT, const float* __restrict__ chT,
    const int* __restrict__ bucket_start, const int* __restrict__ blk_type,
    const int* __restrict__ blk_chunk, const int* __restrict__ rowidx,
    float* __restrict__ out)
{
    __shared__ __align__(16) float bufA[TM][128];   // feat (uses [0..87]) then h2
    __shared__ __align__(16) float bufB[TM][256];   // h1 then h3
    __shared__ int s_row[TM];
    __shared__ int s_rowld[TM];
    __shared__ int s_chain[TM];

    float (*feat)[128] = bufA;
    float (*h1)[256]   = bufB;
    float (*h2)[128]   = bufA;
    float (*h3)[128]   = (float(*)[128])bufB;

    const int t = threadIdx.x;
    const int g = blk_type[blockIdx.x];
    if (g < 0) return;
    const int chunk  = blk_chunk[blockIdx.x];
    const int bstart = bucket_start[g] + chunk * TM;
    const int nrows  = min(TM, bucket_start[g + 1] - bstart);

    if (t < TM) {
        const bool valid = (t < nrows);
        const int rl = rowidx[valid ? (bstart + t) : bstart];
        s_row[t]   = valid ? rl : -1;
        s_rowld[t] = rl;
        s_chain[t] = chain_idx[rl];
        feat[t][45] = 0.f; feat[t][46] = 0.f; feat[t][47] = 0.f;  // coord pad
        feat[t][87] = 0.f;                                        // dihedral pad
    }
    __syncthreads();

    // ---- coord features: xyz_local = O^T (xyz - CA) ----
    if (t < TM * NATOM) {
        const int r = t / NATOM, a = t % NATOM;
        const int rl = s_rowld[r];
        const float* xr = xyz + (size_t)rl * (NATOM * 3);
        const float cax = xr[3], cay = xr[4], caz = xr[5];   // CA_IDX = 1
        const float rx = xr[a*3+0] - cax;
        const float ry = xr[a*3+1] - cay;
        const float rz = xr[a*3+2] - caz;
        const float* O = orientation + (size_t)rl * 9;
        feat[r][a*3+0] = O[0]*rx + O[3]*ry + O[6]*rz;
        feat[r][a*3+1] = O[1]*rx + O[4]*ry + O[7]*rz;
        feat[r][a*3+2] = O[2]*rx + O[5]*ry + O[8]*rz;
    }

    // ---- dihedral angular encoding ----
    if (t < TM * 3) {
        const int r = t / 3, d = t % 3;
        const float x = dihedrals[(size_t)s_rowld[r] * 3 + d];
        float* f = &feat[r][48 + d * 13];
        const float F3 = (float)(1.0 / 3.0);
        f[0]  = x;
        f[1]  = sinf(1.0f * x); f[2]  = sinf(2.0f * x); f[3]  = sinf(3.0f * x);
        f[4]  = sinf(1.0f * x); f[5]  = sinf(0.5f * x); f[6]  = sinf(F3 * x);
        f[7]  = cosf(1.0f * x); f[8]  = cosf(2.0f * x); f[9]  = cosf(3.0f * x);
        f[10] = cosf(1.0f * x); f[11] = cosf(0.5f * x); f[12] = cosf(F3 * x);
    }
    __syncthreads();

    // ---- layer 1, phase A: coord part (48 weight regs live) ----
    {
        float wc[48];
        #pragma unroll
        for (int k = 0; k < 48; ++k)
            wc[k] = W1[(size_t)(ROW_COORD + g * 45 + k) * W1_N + t];
        for (int r = 0; r < TM; ++r) {
            const float4* f4 = (const float4*)&feat[r][0];
            float acc0 = 0.f, acc1 = 0.f;
            #pragma unroll
            for (int k4 = 0; k4 < 12; k4 += 2) {
                const float4 fa = f4[k4], fb = f4[k4+1];
                acc0 += fa.x * wc[k4*4+0]; acc0 += fa.y * wc[k4*4+1];
                acc0 += fa.z * wc[k4*4+2]; acc0 += fa.w * wc[k4*4+3];
                acc1 += fb.x * wc[k4*4+4]; acc1 += fb.y * wc[k4*4+5];
                acc1 += fb.z * wc[k4*4+6]; acc1 += fb.w * wc[k4*4+7];
            }
            h1[r][t] = acc0 + acc1;   // partial (no relu yet)
        }
    }
    // ---- layer 1, phase B: dihedral + base + relu (40 weight regs live) ----
    {
        float wd[40];
        #pragma unroll
        for (int k = 0; k < 40; ++k)
            wd[k] = W1[(size_t)(ROW_DIH + k) * W1_N + t];
        const float base = b1[t] + aaT[g * W1_N + t];
        for (int r = 0; r < TM; ++r) {
            const float4* fd4 = (const float4*)&feat[r][48];
            float acc0 = base + chT[s_chain[r] * W1_N + t] + h1[r][t];
            float acc1 = 0.f;
            #pragma unroll
            for (int k4 = 0; k4 < 10; k4 += 2) {
                const float4 fa = fd4[k4], fb = fd4[k4+1];
                acc0 += fa.x * wd[k4*4+0]; acc0 += fa.y * wd[k4*4+1];
                acc0 += fa.z * wd[k4*4+2]; acc0 += fa.w * wd[k4*4+3];
                acc1 += fb.x * wd[k4*4+4]; acc1 += fb.y * wd[k4*4+5];
                acc1 += fb.z * wd[k4*4+6]; acc1 += fb.w * wd[k4*4+7];
            }
            h1[r][t] = fmaxf(acc0 + acc1, 0.f);
        }
    }
    __syncthreads();   // h1 complete; feat dead -> h2 may overwrite bufA

    const int rg = t >> 5;          // 0..7
    const int cg = t & 31;          // 0..31
    const int r0 = rg * 2, j0 = cg * 4;

    // ---- layer 2: h2 = relu(h1 @ W2 + b2), K=256 ----
    {
        const float4 bv = *(const float4*)&b2[j0];
        float4 c0 = bv, c1 = bv;
        for (int k = 0; k < 256; k += 4) {
            float a0v[4], a1v[4];
            *(float4*)a0v = *(const float4*)&h1[r0+0][k];
            *(float4*)a1v = *(const float4*)&h1[r0+1][k];
            #pragma unroll
            for (int kk = 0; kk < 4; ++kk) {
                const float4 wv = *(const float4*)&W2[(size_t)(k+kk)*128 + j0];
                c0.x += a0v[kk]*wv.x; c0.y += a0v[kk]*wv.y; c0.z += a0v[kk]*wv.z; c0.w += a0v[kk]*wv.w;
                c1.x += a1v[kk]*wv.x; c1.y += a1v[kk]*wv.y; c1.z += a1v[kk]*wv.z; c1.w += a1v[kk]*wv.w;
            }
        }
        __syncthreads();   // all reads of bufA (feat) and h1 done before h2 overwrites bufA
        *(float4*)&h2[r0+0][j0] = relu4(c0);
        *(float4*)&h2[r0+1][j0] = relu4(c1);
    }
    __syncthreads();   // h2 complete; h1 dead -> h3 may overwrite bufB

    // ---- layer 3: h3 = relu(h2 @ W3 + b3), K=128 ----
    {
        const float4 bv = *(const float4*)&b3[j0];
        float4 c0 = bv, c1 = bv;
        for (int k = 0; k < 128; k += 4) {
            float a0v[4], a1v[4];
            *(float4*)a0v = *(const float4*)&h2[r0+0][k];
            *(float4*)a1v = *(const float4*)&h2[r0+1][k];
            #pragma unroll
            for (int kk = 0; kk < 4; ++kk) {
                const float4 wv = *(const float4*)&W3[(size_t)(k+kk)*128 + j0];
                c0.x += a0v[kk]*wv.x; c0.y += a0v[kk]*wv.y; c0.z += a0v[kk]*wv.z; c0.w += a0v[kk]*wv.w;
                c1.x += a1v[kk]*wv.x; c1.y += a1v[kk]*wv.y; c1.z += a1v[kk]*wv.z; c1.w += a1v[kk]*wv.w;
            }
        }
        *(float4*)&h3[r0+0][j0] = relu4(c0);
        *(float4*)&h3[r0+1][j0] = relu4(c1);
    }
    __syncthreads();   // h3 complete

    // ---- layer 4: out = h3 @ W4 + b4, scatter to original rows ----
    {
        const float4 bv = *(const float4*)&b4[j0];
        float4 c0 = bv, c1 = bv;
        for (int k = 0; k < 128; k += 4) {
            float a0v[4], a1v[4];
            *(float4*)a0v = *(const float4*)&h3[r0+0][k];
            *(float4*)a1v = *(const float4*)&h3[r0+1][k];
            #pragma unroll
            for (int kk = 0; kk < 4; ++kk) {
                const float4 wv = *(const float4*)&W4[(size_t)(k+kk)*128 + j0];
                c0.x += a0v[kk]*wv.x; c0.y += a0v[kk]*wv.y; c0.z += a0v[kk]*wv.z; c0.w += a0v[kk]*wv.w;
                c1.x += a1v[kk]*wv.x; c1.y += a1v[kk]*wv.y; c1.z += a1v[kk]*wv.z; c1.w += a1v[kk]*wv.w;
            }
        }
        const int o0 = s_row[r0 + 0];
        const int o1 = s_row[r0 + 1];
        if (o0 >= 0) *(float4*)&out[(size_t)o0 * 128 + j0] = c0;
        if (o1 >= 0) *(float4*)&out[(size_t)o1 * 128 + j0] = c1;
    }
}

extern "C" void kernel_launch(void* const* d_in, const int* in_sizes, int n_in,
                              void* d_out, int out_size, void* d_ws, size_t ws_size,
                              hipStream_t stream) {
    const int*   seq    = (const int*)d_in[0];
    const float* xyz    = (const float*)d_in[1];
    const float* dihed  = (const float*)d_in[2];
    const int*   chain  = (const int*)d_in[3];
    const float* orient = (const float*)d_in[4];
    // d_in[5] = atom_mask: unused by the reference
    const float* aa_emb = (const float*)d_in[6];
    const float* ch_emb = (const float*)d_in[7];
    const float* W1 = (const float*)d_in[8];
    const float* b1 = (const float*)d_in[9];
    const float* W2 = (const float*)d_in[10];
    const float* b2 = (const float*)d_in[11];
    const float* W3 = (const float*)d_in[12];
    const float* b3 = (const float*)d_in[13];
    const float* W4 = (const float*)d_in[14];
    const float* b4 = (const float*)d_in[15];
    float* out = (float*)d_out;

    const int BL = in_sizes[0];           // 16384 rows

    // workspace layout
    float* aaT = (float*)d_ws;                       // 20*256
    float* chT = aaT + N_AA * W1_N;                  // 10*256
    int* bucket_start = (int*)(chT + 10 * W1_N);     // 32
    int* blk_type     = bucket_start + 32;           // MAXBLK
    int* blk_chunk    = blk_type + MAXBLK;           // MAXBLK
    int* rowidx       = blk_chunk + MAXBLK;          // BL

    const int nfused = BL / TM + N_AA;

    prep_kernel<<<31, 1024, 0, stream>>>(seq, aa_emb, ch_emb, W1, BL,
                                         aaT, chT, bucket_start, blk_type, blk_chunk, rowidx);
    fused_kernel<<<nfused, 256, 0, stream>>>(chain, xyz, dihed, orient,
                                             W1, b1, W2, b2, W3, b3, W4, b4,
                                             aaT, chT, bucket_start, blk_type, blk_chunk, rowidx,
                                             out);
}